// Round 12
// baseline (111.998 us; speedup 1.0000x reference)
//
#include <hip/hip_runtime.h>
#include <math.h>

#define EPSC 1e-6f
#define THETAC 1e-3f
#define C1C 1e-4f
#define C2C 9e-4f
#define DEN_EPS 1e-12f

constexpr int Bn = 4, Cn = 16, Hn = 512, Wn = 512;
constexpr int HW = Hn * Wn;          // 262144 = 2^18
constexpr int NP = Bn * HW;          // 1048576
constexpr int TS = 32, RAD = 5, K = 11;
constexpr int HALO = TS + 2 * RAD;   // 42
constexpr int HP = 33;               // horizontal-sum pitch (linear, conflict-free)
constexpr int HSZ = HALO * HP;       // 1386
constexpr int tiles_x = Wn / TS;     // 16
constexpr int NT = tiles_x * (Hn / TS); // 256

// 48-wide aligned window, pitch 49 (all tiled kernels)
constexpr int PW = 49;
constexpr int SSZ = HALO * PW;       // 2058

__device__ __forceinline__ int refl(int i, int n) {
    if (i < 0) i = -i;
    if (i >= n) i = 2 * n - 2 - i;
    return i;
}

__device__ __forceinline__ int swz_tile(int x) { return (x & 7) * (NT / 8) + (x >> 3); }

__device__ __forceinline__ unsigned int bf16pack(float a, float b) {
    unsigned int ua = __float_as_uint(a), ub = __float_as_uint(b);
    ua += 0x7FFFu + ((ua >> 16) & 1u);
    ub += 0x7FFFu + ((ub >> 16) & 1u);
    return (ua >> 16) | (ub & 0xFFFF0000u);
}
__device__ __forceinline__ float bflo(unsigned int v) { return __uint_as_float(v << 16); }
__device__ __forceinline__ float bfhi(unsigned int v) { return __uint_as_float(v & 0xFFFF0000u); }

// merged hbox over packed bf16-pair window -> float2 h (1 ds_write_b64 per slot)
__device__ __forceinline__ void hbox_packed2(const unsigned int* su, float2* h2, int t) {
    if (t < 168) {
        int y = t >> 2, c = t & 3;
        const unsigned int* src = su + y * PW + 8 * c + 3;
        float2* d = h2 + y * HP + 8 * c;
        unsigned int u0 = src[0];
        float a0 = bflo(u0), a1 = bfhi(u0);
#pragma unroll
        for (int dx = 1; dx < K; ++dx) {
            unsigned int u = src[dx];
            a0 += bflo(u); a1 += bfhi(u);
        }
        d[0] = make_float2(a0, a1);
#pragma unroll
        for (int j = 1; j < 8; ++j) {
            unsigned int un = src[j + 10], uo = src[j - 1];
            a0 += bflo(un) - bflo(uo);
            a1 += bfhi(un) - bfhi(uo);
            d[j] = make_float2(a0, a1);
        }
    }
}

// vbox4 over float2 h: 17 ds_read_b64 per thread, paired adds
__device__ __forceinline__ void vbox4_2(const float2* h2, int x, int r0, float2 m[4]) {
    const float inv = 1.f / 121.f;
    const float2* hb = h2 + r0 * HP + x;
    float2 s = hb[0];
#pragma unroll
    for (int dy = 1; dy < K; ++dy) {
        float2 v = hb[dy * HP];
        s.x += v.x; s.y += v.y;
    }
    m[0] = make_float2(s.x * inv, s.y * inv);
#pragma unroll
    for (int j = 1; j < 4; ++j) {
        float2 a = hb[(j + 10) * HP], b = hb[(j - 1) * HP];
        s.x += a.x - b.x;
        s.y += a.y - b.y;
        m[j] = make_float2(s.x * inv, s.y * inv);
    }
}

// ---------------- K1: merged Xs (channel mean) + chi (+partial reductions) ----------------
__global__ void __launch_bounds__(256) k_xschi(
        const float* __restrict__ X, const float* __restrict__ G,
        float* __restrict__ Xs, float* __restrict__ chi,
        float* __restrict__ psum, float* __restrict__ pmin) {
    int t = threadIdx.x;
    if (blockIdx.x < 1024) {
        constexpr int HW4 = HW / 4;
        int i = blockIdx.x * 256 + t;
        int b = i / HW4, off = i - b * HW4;
        const float4* xp = (const float4*)(X + (size_t)b * Cn * HW) + off;
        float4 s = make_float4(0.f, 0.f, 0.f, 0.f);
#pragma unroll
        for (int c = 0; c < Cn; ++c) {
            float4 v = xp[(size_t)c * HW4];
            s.x += v.x; s.y += v.y; s.z += v.z; s.w += v.w;
        }
        const float sc = 1.0f / Cn;
        s.x *= sc; s.y *= sc; s.z *= sc; s.w *= sc;
        ((float4*)Xs)[i] = s;
        return;
    }
    __shared__ float ssum[256], smin[256];
    int bid = blockIdx.x - 1024;
    int base = bid * 1024;
    float ls = 0.f, lm = 1e30f;
#pragma unroll
    for (int k = 0; k < 4; ++k) {
        int p = base + t + k * 256;
        int off = p & (HW - 1);
        int y = off / Wn, x = off & (Wn - 1);
        float g = G[p];
        float gx = (x < Wn - 1) ? G[p + 1] - g : 0.f;
        float gy = (y < Hn - 1) ? G[p + Wn] - g : 0.f;
        float c = sqrtf(gx * gx + gy * gy + EPSC);
        chi[p] = c;
        ls += c;
        lm = fminf(lm, c);
    }
    ssum[t] = ls; smin[t] = lm;
    __syncthreads();
    for (int s = 128; s > 0; s >>= 1) {
        if (t < s) { ssum[t] += ssum[t + s]; smin[t] = fminf(smin[t], smin[t + s]); }
        __syncthreads();
    }
    if (t == 0) { psum[bid] = ssum[0]; pmin[bid] = smin[0]; }
}

// k_ssim hbox over 2 planes at pitch 49 (+3 offset), optionally squared
template <bool SQ>
__device__ __forceinline__ void ss_hbox2(const float* arrs, float* hs, int t) {
    if (t < 168) {
        int pl = t / 84, rem = t - pl * 84;
        int y = rem >> 1, xh = (rem & 1) << 4;
        const float* src = arrs + pl * SSZ + y * PW + xh + 3;
        float* hd = hs + pl * HSZ + y * HP + xh;
        float v = src[0];
        float s = SQ ? v * v : v;
#pragma unroll
        for (int dx = 1; dx < K; ++dx) { float u = src[dx]; s += SQ ? u * u : u; }
        hd[0] = s;
#pragma unroll
        for (int j = 1; j < 16; ++j) {
            float un = src[j + 10], uo = src[j - 1];
            s += (SQ ? un * un : un) - (SQ ? uo * uo : uo);
            hd[j] = s;
        }
    }
}

__device__ __forceinline__ void ss_vbox(const float* hs, int x, int r0, float m[4]) {
    const float inv_area = 1.f / (float)(K * K);
    const float* hb = hs + r0 * HP + x;
    float s = hb[0];
#pragma unroll
    for (int dy = 1; dy < K; ++dy) s += hb[dy * HP];
    m[0] = s * inv_area;
#pragma unroll
    for (int j = 1; j < 4; ++j) {
        s += hb[(j + 10) * HP] - hb[(j - 1) * HP];
        m[j] = s * inv_area;
    }
}

// ---------------- K3: merged ssim r=5 & r=1 + plane outputs + reductions ----------------
__global__ void __launch_bounds__(256) k_ssim(
        const float* __restrict__ Xs, const float* __restrict__ G,
        float* __restrict__ muG, float* __restrict__ varGr, float* __restrict__ taur,
        float* __restrict__ chig, float* __restrict__ nu,
        float* __restrict__ ps1, float* __restrict__ ps2) {
    __shared__ float arrs[2 * SSZ];   // x, g windows (pitch 49, 48-wide aligned)
    __shared__ float hs[2 * HSZ];
    float* red1 = hs;
    float* red2 = hs + HSZ;
    int t = threadIdx.x;
    int b = blockIdx.y;
    int tile = swz_tile(blockIdx.x);
    int tx0 = (tile % tiles_x) * TS, ty0 = (tile / tiles_x) * TS;
    const float* Xp = Xs + (size_t)b * HW;
    const float* Gp = G + (size_t)b * HW;
    for (int u = t; u < HALO * 12; u += 256) {
        int ly = u / 12, k = u - ly * 12;
        int gy = refl(ty0 - 5 + ly, Hn);
        int col = tx0 - 8 + 4 * k;
        int o = ly * PW + 4 * k;
        if (col >= 0 && col <= Wn - 4) {
            float4 xv = *(const float4*)(Xp + gy * Wn + col);
            float4 gv = *(const float4*)(Gp + gy * Wn + col);
            arrs[o] = xv.x; arrs[o + 1] = xv.y; arrs[o + 2] = xv.z; arrs[o + 3] = xv.w;
            arrs[SSZ + o] = gv.x; arrs[SSZ + o + 1] = gv.y;
            arrs[SSZ + o + 2] = gv.z; arrs[SSZ + o + 3] = gv.w;
        } else {
#pragma unroll
            for (int i = 0; i < 4; ++i) {
                int gx = refl(col + i, Wn);
                arrs[o + i] = Xp[gy * Wn + gx];
                arrs[SSZ + o + i] = Gp[gy * Wn + gx];
            }
        }
    }
    __syncthreads();

    int x = t & 31, g = t >> 5, r0 = g * 4;
    float acc[5][4];
    ss_hbox2<false>(arrs, hs, t);
    __syncthreads();
    ss_vbox(hs, x, r0, acc[0]);
    ss_vbox(hs + HSZ, x, r0, acc[1]);
    __syncthreads();
    ss_hbox2<true>(arrs, hs, t);
    __syncthreads();
    ss_vbox(hs, x, r0, acc[2]);
    ss_vbox(hs + HSZ, x, r0, acc[3]);
    __syncthreads();
    if (t < 168) {   // x*g plane, 8-wide chunks
        int y = t >> 2, c = t & 3;
        const float* sx = arrs + y * PW + 8 * c + 3;
        const float* sg = arrs + SSZ + y * PW + 8 * c + 3;
        float* hd = hs + y * HP + 8 * c;
        float s = sx[0] * sg[0];
#pragma unroll
        for (int dx = 1; dx < K; ++dx) s += sx[dx] * sg[dx];
        hd[0] = s;
#pragma unroll
        for (int j = 1; j < 8; ++j) {
            s += sx[j + 10] * sg[j + 10] - sx[j - 1] * sg[j - 1];
            hd[j] = s;
        }
    }
    __syncthreads();
    ss_vbox(hs, x, r0, acc[4]);

    float m1[5][4];
#pragma unroll
    for (int p = 0; p < 5; ++p) {
        float h3[6];
#pragma unroll
        for (int j = 0; j < 6; ++j) {
            int bb = (r0 + 4 + j) * PW + (x + 7);
            float s = 0.f;
#pragma unroll
            for (int i = 0; i < 3; ++i) {
                float vx = arrs[bb + i], vg = arrs[SSZ + bb + i];
                float v = (p == 0) ? vx : (p == 1) ? vg : (p == 2) ? vx * vx
                          : (p == 3) ? vg * vg : vx * vg;
                s += v;
            }
            h3[j] = s;
        }
#pragma unroll
        for (int j = 0; j < 4; ++j)
            m1[p][j] = (h3[j] + h3[j + 1] + h3[j + 2]) * (1.f / 9.f);
    }

    float l1 = 0.f, l2 = 0.f;
    float outv[5][4];
#pragma unroll
    for (int j = 0; j < 4; ++j) {
        float mux = acc[0][j], mug = acc[1][j], mxx = acc[2][j], mgg = acc[3][j], mxy = acc[4][j];
        float sx2 = fmaxf(mxx - mux * mux, 0.f);
        float sg2 = fmaxf(mgg - mug * mug, 0.f);
        float sxy = mxy - mux * mug;
        float num = (2.f * mux * mug + C1C) * (2.f * sxy + C2C);
        float den = (mux * mux + mug * mug + C1C) * (sx2 + sg2 + C2C);
        float tr_ = fminf(fmaxf((num / (den + DEN_EPS) + 1.f) * 0.5f, 0.f), 1.f);

        float n0 = m1[0][j], n1 = m1[1][j], n2 = m1[2][j], n3 = m1[3][j], n4 = m1[4][j];
        float sx21 = fmaxf(n2 - n0 * n0, 0.f);
        float sg21 = fmaxf(n3 - n1 * n1, 0.f);
        float sxy1 = n4 - n0 * n1;
        float num1 = (2.f * n0 * n1 + C1C) * (2.f * sxy1 + C2C);
        float den1 = (n0 * n0 + n1 * n1 + C1C) * (sx21 + sg21 + C2C);
        float t1_ = fminf(fmaxf((num1 / (den1 + DEN_EPS) + 1.f) * 0.5f, 0.f), 1.f);

        float chig_ = sqrtf(sg21 + EPSC) * sqrtf(sg2 + EPSC);
        float nu_ = fmaxf(t1_ * tr_, 0.f);
        outv[0][j] = mug; outv[1][j] = sg2; outv[2][j] = tr_;
        outv[3][j] = chig_; outv[4][j] = nu_;
        l1 += 1.f / (chig_ + EPSC);
        l2 += 1.f / (nu_ + THETAC);
    }
#pragma unroll
    for (int j = 0; j < 4; ++j) {
        int gp = b * HW + (ty0 + r0 + j) * Wn + (tx0 + x);
        muG[gp] = outv[0][j];
        varGr[gp] = outv[1][j];
        taur[gp] = outv[2][j];
        chig[gp] = outv[3][j];
        nu[gp] = outv[4][j];
    }
    __syncthreads();
    red1[t] = l1; red2[t] = l2;
    __syncthreads();
    for (int s = 128; s > 0; s >>= 1) {
        if (t < s) { red1[t] += red1[t + s]; red2[t] += red2[t + s]; }
        __syncthreads();
    }
    if (t == 0) {
        ps1[b * NT + blockIdx.x] = red1[0];
        ps2[b * NT + blockIdx.x] = red2[0];
    }
}

// ---------------- K red ----------------
__global__ void __launch_bounds__(256) k_red(
        const float* __restrict__ psum, const float* __restrict__ pmin,
        const float* __restrict__ s1, const float* __restrict__ s2,
        float* __restrict__ sc) {
    __shared__ float a1[256], a2[256];
    int t = threadIdx.x;
    if (blockIdx.x < 4) {
        int b = blockIdx.x;
        a1[t] = psum[b * 256 + t];
        a2[t] = pmin[b * 256 + t];
        __syncthreads();
        for (int s = 128; s > 0; s >>= 1) {
            if (t < s) { a1[t] += a1[t + s]; a2[t] = fminf(a2[t], a2[t + s]); }
            __syncthreads();
        }
        if (t == 0) {
            float mu = a1[0] / (float)HW;
            sc[b] = mu;
            sc[4 + b] = fmaxf(mu - a2[0], EPSC);
        }
    } else {
        int b = blockIdx.x - 4;
        a1[t] = s1[b * 256 + t];
        a2[t] = s2[b * 256 + t];
        __syncthreads();
        for (int s = 128; s > 0; s >>= 1) {
            if (t < s) { a1[t] += a1[t + s]; a2[t] += a2[t + s]; }
            __syncthreads();
        }
        if (t == 0) {
            sc[8 + b] = a1[0] / (float)HW;
            sc[12 + b] = a2[0] / (float)HW;
        }
    }
}

// ---------------- K4: packed (P, invD, muG) plane, 4-wide ----------------
__global__ void __launch_bounds__(256) k_pd(
        const float* __restrict__ chi, const float* __restrict__ chig,
        const float* __restrict__ nu, const float* __restrict__ taur,
        const float* __restrict__ vr, const float* __restrict__ muG,
        const float* __restrict__ sc, float4* __restrict__ PDM) {
    int i = blockIdx.x * 256 + threadIdx.x;
    int p0 = i * 4;
    int b = p0 >> 18;
    float mu = sc[b], eta = sc[4 + b], imc = sc[8 + b], imn = sc[12 + b];
    float4 c4 = ((const float4*)chi)[i];
    float4 cg4 = ((const float4*)chig)[i];
    float4 nu4 = ((const float4*)nu)[i];
    float4 tr4 = ((const float4*)taur)[i];
    float4 vr4 = ((const float4*)vr)[i];
    float4 mg4 = ((const float4*)muG)[i];
    float cc[4] = {c4.x, c4.y, c4.z, c4.w};
    float gg[4] = {cg4.x, cg4.y, cg4.z, cg4.w};
    float nn[4] = {nu4.x, nu4.y, nu4.z, nu4.w};
    float tt[4] = {tr4.x, tr4.y, tr4.z, tr4.w};
    float vv[4] = {vr4.x, vr4.y, vr4.z, vr4.w};
    float mm[4] = {mg4.x, mg4.y, mg4.z, mg4.w};
#pragma unroll
    for (int j = 0; j < 4; ++j) {
        float gamma = 1.f / (1.f + expf(-eta * (cc[j] - mu)));
        float GG = (gg[j] + EPSC) * imc;
        float w_e = 1.0f / (GG + EPSC);
        float GS = (nn[j] + THETAC) * imn;
        float w_s = gamma / (GS + EPSC);
        float P = w_e * gamma + w_s * tt[j];
        float D = vv[j] + EPSC + w_e + w_s + EPSC;
        PDM[p0 + j] = make_float4(P, 1.0f / D, mm[j], 0.f);
    }
}

// ---------------- K5: per-channel a,b (packed bf16 window, float2 h, 2 barriers) ----------------
__global__ void __launch_bounds__(256) k_ab(
        const float* __restrict__ X, const float* __restrict__ G,
        const float4* __restrict__ PDM, unsigned int* __restrict__ AB) {
    __shared__ unsigned int su[SSZ];     // packed (X, X*G) bf16 pairs, pitch 49
    __shared__ float2 h2[HSZ];           // (hsumX, hsumXG)
    int t = threadIdx.x;
    int pc = blockIdx.y, b = pc >> 4;
    int tile = swz_tile(blockIdx.x);
    int tx0 = (tile & 15) * TS, ty0 = (tile >> 4) * TS;
    int x = t & 31, wg = t >> 5, r0 = wg * 4;
    // prefetch epilogue operands (latency hides under staging/hbox)
    const float4* Pp = PDM + (size_t)b * HW;
    int pbase = (ty0 + r0) * Wn + tx0 + x;
    float4 pdm[4];
#pragma unroll
    for (int j = 0; j < 4; ++j) pdm[j] = Pp[pbase + j * Wn];

    const float* Xp = X + (size_t)pc * HW;
    const float* Gp = G + (size_t)b * HW;
    // unified staging: per-chunk validity, vec4 fast path; pack (X, X*G) -> bf16 pair
    for (int u = t; u < HALO * 12; u += 256) {
        int ly = u / 12, k = u - ly * 12;
        int gy = refl(ty0 - 5 + ly, Hn);
        int col = tx0 - 8 + 4 * k;
        int o = ly * PW + 4 * k;
        if (col >= 0 && col <= Wn - 4) {
            float4 xv = *(const float4*)(Xp + gy * Wn + col);
            float4 gv = *(const float4*)(Gp + gy * Wn + col);
            su[o]     = bf16pack(xv.x, xv.x * gv.x);
            su[o + 1] = bf16pack(xv.y, xv.y * gv.y);
            su[o + 2] = bf16pack(xv.z, xv.z * gv.z);
            su[o + 3] = bf16pack(xv.w, xv.w * gv.w);
        } else {
#pragma unroll
            for (int i = 0; i < 4; ++i) {
                int gx = refl(col + i, Wn);
                float xv = Xp[gy * Wn + gx], gv = Gp[gy * Wn + gx];
                su[o + i] = bf16pack(xv, xv * gv);
            }
        }
    }
    __syncthreads();
    hbox_packed2(su, h2, t);   // h2 = (hsum X, hsum X*G)
    __syncthreads();

    float2 m[4];
    vbox4_2(h2, x, r0, m);

    unsigned int* Ap = AB + (size_t)pc * HW;
#pragma unroll
    for (int j = 0; j < 4; ++j) {
        float mx = m[j].x, mxg = m[j].y;
        float a = (mxg - pdm[j].z * mx + pdm[j].x) * pdm[j].y;  // *invD
        float bb = mx - a * pdm[j].z;
        Ap[pbase + j * Wn] = bf16pack(a, bb);
    }
}

// ---------------- K6: out = box11(a)*G + box11(b) (packed su, float2 h, 2 barriers) ----------------
__global__ void __launch_bounds__(256) k_out(
        const unsigned int* __restrict__ AB, const float* __restrict__ G,
        float* __restrict__ out) {
    __shared__ unsigned int su[SSZ];     // packed (a,b), pitch 49
    __shared__ float2 h2[HSZ];           // (hsum a, hsum b)
    int t = threadIdx.x;
    int pc = blockIdx.y, b = pc >> 4;
    int tile = swz_tile(blockIdx.x);
    int tx0 = (tile & 15) * TS, ty0 = (tile >> 4) * TS;
    int x = t & 31, wg = t >> 5, r0 = wg * 4;
    // prefetch G for epilogue
    const float* Gp = G + (size_t)b * HW;
    int pbase = (ty0 + r0) * Wn + tx0 + x;
    float gv[4];
#pragma unroll
    for (int j = 0; j < 4; ++j) gv[j] = Gp[pbase + j * Wn];

    const unsigned int* Ap = AB + (size_t)pc * HW;
    for (int u = t; u < HALO * 12; u += 256) {
        int ly = u / 12, k = u - ly * 12;
        int gy = refl(ty0 - 5 + ly, Hn);
        int col = tx0 - 8 + 4 * k;
        int o = ly * PW + 4 * k;
        if (col >= 0 && col <= Wn - 4) {
            uint4 v = *(const uint4*)(Ap + gy * Wn + col);
            su[o] = v.x; su[o + 1] = v.y; su[o + 2] = v.z; su[o + 3] = v.w;
        } else {
#pragma unroll
            for (int i = 0; i < 4; ++i) {
                int gx = refl(col + i, Wn);
                su[o + i] = Ap[gy * Wn + gx];
            }
        }
    }
    __syncthreads();
    hbox_packed2(su, h2, t);   // h2 = (hsum a, hsum b)
    __syncthreads();

    float2 m[4];
    vbox4_2(h2, x, r0, m);

    float* op = out + (size_t)pc * HW;
#pragma unroll
    for (int j = 0; j < 4; ++j)
        op[pbase + j * Wn] = m[j].x * gv[j] + m[j].y;
}

extern "C" void kernel_launch(void* const* d_in, const int* in_sizes, int n_in,
                              void* d_out, int out_size, void* d_ws, size_t ws_size,
                              hipStream_t stream) {
    const float* X = (const float*)d_in[0];
    const float* G = (const float*)d_in[1];
    float* out = (float*)d_out;
    float* ws = (float*)d_ws;

    float* Xs   = ws + 0 * (size_t)NP;
    float* chi  = ws + 1 * (size_t)NP;
    float* taur = ws + 2 * (size_t)NP;
    float* vr   = ws + 3 * (size_t)NP;
    float* muG  = ws + 4 * (size_t)NP;
    float* chig = ws + 5 * (size_t)NP;
    float* nu   = ws + 6 * (size_t)NP;
    float4* PDM = (float4*)(ws + 7 * (size_t)NP);            // 4*NP floats
    unsigned int* AB = (unsigned int*)(ws + 11 * (size_t)NP); // NX uints
    float* psum = ws + 43 * (size_t)NP;
    float* pmin = psum + 1024;
    float* ps1  = pmin + 1024;
    float* ps2  = ps1 + 1024;
    float* sc   = ps2 + 1024;   // 16 scalars

    dim3 blk(256);
    k_xschi<<<2048, blk, 0, stream>>>(X, G, Xs, chi, psum, pmin);

    dim3 gplane(NT, Bn);
    k_ssim<<<gplane, blk, 0, stream>>>(Xs, G, muG, vr, taur, chig, nu, ps1, ps2);
    k_red<<<8, blk, 0, stream>>>(psum, pmin, ps1, ps2, sc);
    k_pd<<<(NP / 4) / 256, blk, 0, stream>>>(chi, chig, nu, taur, vr, muG, sc, PDM);

    dim3 gchan(NT, Bn * Cn);
    k_ab<<<gchan, blk, 0, stream>>>(X, G, PDM, AB);
    k_out<<<gchan, blk, 0, stream>>>(AB, G, out);
}